// Round 7
// baseline (98.227 us; speedup 1.0000x reference)
//
#include <hip/hip_runtime.h>
#include <math.h>

#define NFFT     1024
#define HOP      256
#define NFRAMES  622
#define NBATCH   32
#define XLEN     160000
#define TILE_T   16
#define NPAIR    8
#define ROW      1234      // padded float2 stride per array
#define KBINS    513
#define NT       512
#define NTILES   39        // tiles per batch row
#define NTILES_TOT (NTILES*NBATCH)   // 1248
#define NPERSIST 512       // 2 blocks/CU x 256 CUs

// multi-digit pad (float2 units): PAD(i) = i + 2(i>>4) + 4(i>>6) + 8(i>>8).
#define PAD(i)   ((i) + 2*((i)>>4) + 4*((i)>>6) + 8*((i)>>8))

#define C1 0.9238795325112867f   // cos(pi/8)
#define S1 0.3826834323650898f   // sin(pi/8)
#define C2 0.7071067811865476f   // cos(pi/4)

__device__ __forceinline__ float2 cmul(float2 a, float2 b) {
    return make_float2(a.x*b.x - a.y*b.y, a.x*b.y + a.y*b.x);
}
__device__ __forceinline__ float2 csqr(float2 a) {
    return make_float2(a.x*a.x - a.y*a.y, 2.0f*a.x*a.y);
}

// hardware sin/cos: input in REVOLUTIONS; args < 0.25 so no range reduction.
__device__ __forceinline__ float2 w_of_rev(float f) {
    float s, c;
    asm("v_sin_f32 %0, %1" : "=v"(s) : "v"(f));
    asm("v_cos_f32 %0, %1" : "=v"(c) : "v"(f));
    return make_float2(c, s);
}

__device__ __forceinline__ void bfly4(float2& a, float2& b, float2& c, float2& d,
                                      float2 w1, float2 w2, float2 w3) {
    float2 apc = make_float2(a.x + c.x, a.y + c.y);
    float2 amc = make_float2(a.x - c.x, a.y - c.y);
    float2 bpd = make_float2(b.x + d.x, b.y + d.y);
    float2 bmd = make_float2(b.x - d.x, b.y - d.y);
    float2 y0 = make_float2(apc.x + bpd.x, apc.y + bpd.y);
    float2 y2 = make_float2(apc.x - bpd.x, apc.y - bpd.y);
    float2 y1 = make_float2(amc.x + bmd.y, amc.y - bmd.x);  // amc - i*bmd
    float2 y3 = make_float2(amc.x - bmd.y, amc.y + bmd.x);  // amc + i*bmd
    a = y0; b = cmul(w1, y1); c = cmul(w2, y2); d = cmul(w3, y3);
}
__device__ __forceinline__ void bfly4_nw(float2& a, float2& b, float2& c, float2& d) {
    float2 apc = make_float2(a.x + c.x, a.y + c.y);
    float2 amc = make_float2(a.x - c.x, a.y - c.y);
    float2 bpd = make_float2(b.x + d.x, b.y + d.y);
    float2 bmd = make_float2(b.x - d.x, b.y - d.y);
    a = make_float2(apc.x + bpd.x, apc.y + bpd.y);
    b = make_float2(amc.x + bmd.y, amc.y - bmd.x);
    c = make_float2(apc.x - bpd.x, apc.y - bpd.y);
    d = make_float2(amc.x - bmd.y, amc.y + bmd.x);
}

// wave-internal LDS ordering fence (HW keeps a wave's DS ops in order).
__device__ __forceinline__ void fence() {
    asm volatile("s_waitcnt lgkmcnt(0)" ::: "memory");
    __builtin_amdgcn_sched_barrier(0);
}
// block barrier WITHOUT vmcnt drain: LDS ordering only; outstanding global
// stores/loads keep flowing. sched_barrier pins compiler motion both sides.
__device__ __forceinline__ void lgk_barrier() {
    __builtin_amdgcn_sched_barrier(0);
    asm volatile("s_waitcnt lgkmcnt(0)" ::: "memory");
    __builtin_amdgcn_s_barrier();
    __builtin_amdgcn_sched_barrier(0);
}

// ~17-instr atan2: v_rcp (1 ulp) + deg-11 minimax odd poly, err ~5e-6 rad.
__device__ __forceinline__ float fast_atan2f(float y, float x) {
    const float ax = fabsf(x), ay = fabsf(y);
    const float mx = fmaxf(ax, ay), mn = fminf(ax, ay);
    float r = mn * __builtin_amdgcn_rcpf(mx);
    if (mx == 0.0f) r = 0.0f;
    const float t = r * r;
    float p = fmaf(t, -0.01172120f, 0.05265332f);
    p = fmaf(t, p, -0.11643287f);
    p = fmaf(t, p, 0.19354346f);
    p = fmaf(t, p, -0.33262347f);
    p = fmaf(t, p, 0.99997726f);
    float a = r * p;
    a = (ay > ax) ? (1.5707963267948966f - a) : a;
    a = (x < 0.0f) ? (3.14159265358979323f - a) : a;
    return copysignf(a, y);
}

// exact /39 for 0 <= v < 1248*2: magic verified at boundaries 38/39/77/78/1208/1209/1247
__device__ __forceinline__ int div39(int v) { return (v * 26887) >> 20; }

__global__ __launch_bounds__(NT, 4)
void spec_kernel(const float* __restrict__ x, const float* __restrict__ win,
                 float* __restrict__ out, unsigned int* __restrict__ counter)
{
    __shared__ __align__(16) float2 zb[NPAIR * ROW];  // 78,976 B -> 2 blocks/CU
    __shared__ int sm_next;

    const int tid = threadIdx.x;
    const int wv  = tid >> 6;     // wave id == packed-array id
    const int ln  = tid & 63;

    // ---- first tile via work-steal counter ----
    if (tid == 0) sm_next = (int)atomicAdd(counter, 1u);
    __syncthreads();
    int tile = sm_next;
    __syncthreads();              // all reads done before tid0's next write

    // ---- initial prefetch into registers ----
    float4 pa[4], pb[4];
    if (tile < NTILES_TOT) {
        const int bb = div39(tile);
        const int t0 = (tile - bb * NTILES) * TILE_T;
        const float* xb = x + (size_t)bb * XLEN;
        const int f0 = t0 + 2*wv, f1 = f0 + 1;
        const bool v0 = (f0 < NFRAMES), v1 = (f1 < NFRAMES);
        #pragma unroll
        for (int q = 0; q < 4; ++q) {
            const int n0 = (q << 8) + (ln << 2);
            pa[q] = v0 ? *reinterpret_cast<const float4*>(&xb[f0*HOP + n0])
                       : make_float4(0.f,0.f,0.f,0.f);
            pb[q] = v1 ? *reinterpret_cast<const float4*>(&xb[f1*HOP + n0])
                       : make_float4(0.f,0.f,0.f,0.f);
        }
    }

    while (tile < NTILES_TOT) {
        const int bb = div39(tile);
        const int t0 = (tile - bb * NTILES) * TILE_T;

        // ---- A: window (from L1-resident win) + stage own array to LDS ----
        {
            float4* D4 = reinterpret_cast<float4*>(
                &zb[wv*ROW + 4*ln + 2*(ln>>2) + 4*(ln>>4)]);
            #pragma unroll
            for (int q = 0; q < 4; ++q) {
                const int n0 = (q << 8) + (ln << 2);
                const float4 w4 = *reinterpret_cast<const float4*>(&win[n0]);
                D4[156*q]     = make_float4(w4.x*pa[q].x, w4.x*pb[q].x,
                                            w4.y*pa[q].y, w4.y*pb[q].y);
                D4[156*q + 1] = make_float4(w4.z*pa[q].z, w4.z*pb[q].z,
                                            w4.w*pa[q].w, w4.w*pb[q].w);
            }
        }
        fence();

        // ---- B: fused stages 0+1 (radix-16 in registers) ----
        {
            float2* p = &zb[wv*ROW + ln + 2*(ln>>4)];
            float2 E[16];
            #pragma unroll
            for (int j = 0; j < 16; ++j) E[j] = p[76*j + 8*(j>>2)];
            const float2 wc = w_of_rev((float)ln * (-1.0f/1024.0f));   // W_1024^ln
            #pragma unroll
            for (int q = 0; q < 4; ++q) {
                float2 w1;
                if      (q == 0) w1 = wc;
                else if (q == 1) w1 = cmul(wc, make_float2(C1, -S1));
                else if (q == 2) w1 = cmul(wc, make_float2(C2, -C2));
                else             w1 = cmul(wc, make_float2(S1, -C1));
                float2 w2 = csqr(w1), w3 = cmul(w1, w2);
                bfly4(E[q], E[q+4], E[q+8], E[q+12], w1, w2, w3);
            }
            const float2 wb  = csqr(csqr(wc));                         // W_1024^{4ln}
            const float2 wb2 = csqr(wb), wb3 = cmul(wb, wb2);
            #pragma unroll
            for (int u = 0; u < 4; ++u)
                bfly4(E[4*u], E[4*u+1], E[4*u+2], E[4*u+3], wb, wb2, wb3);
            #pragma unroll
            for (int j = 0; j < 16; ++j) p[76*j + 8*(j>>2)] = E[j];
        }
        fence();

        // ---- stage 2 (M=16) ----
        {
            const int m = ln & 15, h = ln >> 4;
            float2* p = &zb[wv*ROW + 76*h + m];
            const float2 w1 = w_of_rev((float)m * (-1.0f/64.0f));      // W_64^m
            const float2 w2 = csqr(w1), w3 = cmul(w1, w2);
            #pragma unroll
            for (int u = 0; u < 4; ++u) {
                float2 a  = p[312*u],      bb2 = p[312*u + 18];
                float2 cc = p[312*u + 36], dd  = p[312*u + 54];
                bfly4(a, bb2, cc, dd, w1, w2, w3);
                p[312*u]      = a;   p[312*u + 18] = bb2;
                p[312*u + 36] = cc;  p[312*u + 54] = dd;
            }
        }
        fence();

        // ---- fused stages 3+4 (registers, constant twiddles), b128 ----
        {
            float4* p = reinterpret_cast<float4*>(
                &zb[wv*ROW + 18*ln + 4*(ln>>2) + 8*(ln>>4)]);
            float2 F[16];
            #pragma unroll
            for (int r = 0; r < 8; ++r) {
                const float4 v = p[r];
                F[2*r]   = make_float2(v.x, v.y);
                F[2*r+1] = make_float2(v.z, v.w);
            }
            bfly4_nw(F[0], F[4], F[8],  F[12]);
            bfly4(F[1], F[5], F[9],  F[13], make_float2(C1,-S1), make_float2(C2,-C2), make_float2(S1,-C1));
            bfly4(F[2], F[6], F[10], F[14], make_float2(C2,-C2), make_float2(0.f,-1.f), make_float2(-C2,-C2));
            bfly4(F[3], F[7], F[11], F[15], make_float2(S1,-C1), make_float2(-C2,-C2), make_float2(-C1, S1));
            bfly4_nw(F[0],  F[1],  F[2],  F[3]);
            bfly4_nw(F[4],  F[5],  F[6],  F[7]);
            bfly4_nw(F[8],  F[9],  F[10], F[11]);
            bfly4_nw(F[12], F[13], F[14], F[15]);
            #pragma unroll
            for (int r = 0; r < 8; ++r)
                p[r] = make_float4(F[2*r].x, F[2*r].y, F[2*r+1].x, F[2*r+1].y);
        }

        // ---- grab next tile, then publish arrays + sm_next together ----
        if (tid == 0) sm_next = (int)atomicAdd(counter, 1u);
        lgk_barrier();
        const int nxt = sm_next;

        // ---- prefetch next tile's x into registers (retires under output) ----
        if (nxt < NTILES_TOT) {
            const int nb  = div39(nxt);
            const int nt0 = (nxt - nb * NTILES) * TILE_T;
            const float* xb = x + (size_t)nb * XLEN;
            const int f0 = nt0 + 2*wv, f1 = f0 + 1;
            const bool v0 = (f0 < NFRAMES), v1 = (f1 < NFRAMES);
            #pragma unroll
            for (int q = 0; q < 4; ++q) {
                const int n0 = (q << 8) + (ln << 2);
                pa[q] = v0 ? *reinterpret_cast<const float4*>(&xb[f0*HOP + n0])
                           : make_float4(0.f,0.f,0.f,0.f);
                pb[q] = v1 ? *reinterpret_cast<const float4*>(&xb[f1*HOP + n0])
                           : make_float4(0.f,0.f,0.f,0.f);
            }
        }

        // ---- output: unpack + mag/phase; 64-B write runs per (k, tile) ----
        {
            const int kg  = tid >> 3;          // 0..63
            const int jj  = tid & 7;           // frame pair
            const int t_e = t0 + 2*jj;
            const bool tval = (t_e < NFRAMES);

            const int R1 = ((kg & 3) << 8) | ((kg & 12) << 4) | (kg & 48);
            const int km = 64 - kg;
            const int R2 = ((km & 3) << 8) | ((km & 12) << 4) | (km & 48);
            const int J0 = (kg == 0) ? 16 : 15;
            const float2* zp1 = &zb[jj*ROW + PAD(R1)];
            const float2* zp2 = &zb[jj*ROW + PAD(R2)];

            float* magp = out;                                        // [32][513][622]
            float* php  = out + (size_t)NBATCH * KBINS * NFRAMES;     // [32][1024][622]
            const size_t magbase = (size_t)bb * KBINS * NFRAMES + t_e;
            const size_t phbase  = (size_t)bb * NFFT  * NFRAMES + t_e;

            if (tval) {
                #pragma unroll
                for (int it = 0; it < 9; ++it) {
                    if (it == 8 && kg != 0) break;         // only k=512 remains
                    const int k  = kg + (it << 6);
                    const int c1 = ((it & 3) << 2) | (it >> 2);        // rev4(64it)
                    const int j2 = (J0 - it) & 15;
                    const int c2 = ((j2 & 3) << 2) | (j2 >> 2);
                    const float2 z1 = zp1[c1];
                    const float2 z2 = zp2[c2];
                    const float re_e = 0.5f*(z1.x + z2.x);
                    const float im_e = 0.5f*(z1.y - z2.y);  // exact +0.0 at k=0,512
                    const float re_o = 0.5f*(z1.y + z2.y);
                    const float im_o = 0.5f*(z2.x - z1.x);
                    *reinterpret_cast<float2*>(&magp[magbase + (size_t)k * NFRAMES]) =
                        make_float2(fmaf(re_e, re_e, im_e*im_e),
                                    fmaf(re_o, re_o, im_o*im_o));
                    const float ph_e = fast_atan2f(im_e, re_e);
                    const float ph_o = fast_atan2f(im_o, re_o);
                    *reinterpret_cast<float2*>(&php[phbase + (size_t)k * NFRAMES]) =
                        make_float2(ph_e, ph_o);
                    if (k != 0 && k != 512) {
                        // atan2 odd in y INCLUDING signed zeros -> sign flip
                        *reinterpret_cast<float2*>(&php[phbase + (size_t)(NFFT - k) * NFRAMES]) =
                            make_float2(-ph_e, -ph_o);
                    }
                }
            }
        }
        lgk_barrier();   // output reads done -> safe to overwrite LDS
        tile = nxt;
    }
}

extern "C" void kernel_launch(void* const* d_in, const int* in_sizes, int n_in,
                              void* d_out, int out_size, void* d_ws, size_t ws_size,
                              hipStream_t stream) {
    const float* x  = (const float*)d_in[0];
    const float* rw = (const float*)d_in[1];   // row 0 = fp32 hanning window
    float* out = (float*)d_out;
    hipMemsetAsync(d_ws, 0, sizeof(unsigned int), stream);   // reset steal counter
    spec_kernel<<<dim3(NPERSIST, 1, 1), dim3(NT, 1, 1), 0, stream>>>(
        x, rw, out, (unsigned int*)d_ws);
}

// Round 8
// 56.502 us; speedup vs baseline: 1.7385x; 1.7385x over previous
//
#include <hip/hip_runtime.h>
#include <math.h>

#define NFFT     1024
#define HOP      256
#define NFRAMES  622
#define NBATCH   32
#define XLEN     160000
#define TILE_T   16
#define NPAIR    8
#define ROW      1234            // padded float2 stride per array (R5-verified)
#define ABUF     (NPAIR*ROW)     // float2 per buffer
#define KBINS    513
#define NT       1024
#define NTILES   39              // tiles per batch row
#define NBLK     256             // 1 persistent block per CU

// multi-digit pad (float2 units): PAD(i) = i + 2(i>>4) + 4(i>>6) + 8(i>>8).
#define PAD(i)   ((i) + 2*((i)>>4) + 4*((i)>>6) + 8*((i)>>8))

#define C1 0.9238795325112867f   // cos(pi/8)
#define S1 0.3826834323650898f   // sin(pi/8)
#define C2 0.7071067811865476f   // cos(pi/4)

__device__ __forceinline__ float2 cmul(float2 a, float2 b) {
    return make_float2(a.x*b.x - a.y*b.y, a.x*b.y + a.y*b.x);
}
__device__ __forceinline__ float2 csqr(float2 a) {
    return make_float2(a.x*a.x - a.y*a.y, 2.0f*a.x*a.y);
}

// hardware sin/cos: input in REVOLUTIONS; args < 0.25 so no range reduction.
__device__ __forceinline__ float2 w_of_rev(float f) {
    float s, c;
    asm("v_sin_f32 %0, %1" : "=v"(s) : "v"(f));
    asm("v_cos_f32 %0, %1" : "=v"(c) : "v"(f));
    return make_float2(c, s);
}

__device__ __forceinline__ void bfly4(float2& a, float2& b, float2& c, float2& d,
                                      float2 w1, float2 w2, float2 w3) {
    float2 apc = make_float2(a.x + c.x, a.y + c.y);
    float2 amc = make_float2(a.x - c.x, a.y - c.y);
    float2 bpd = make_float2(b.x + d.x, b.y + d.y);
    float2 bmd = make_float2(b.x - d.x, b.y - d.y);
    float2 y0 = make_float2(apc.x + bpd.x, apc.y + bpd.y);
    float2 y2 = make_float2(apc.x - bpd.x, apc.y - bpd.y);
    float2 y1 = make_float2(amc.x + bmd.y, amc.y - bmd.x);  // amc - i*bmd
    float2 y3 = make_float2(amc.x - bmd.y, amc.y + bmd.x);  // amc + i*bmd
    a = y0; b = cmul(w1, y1); c = cmul(w2, y2); d = cmul(w3, y3);
}
__device__ __forceinline__ void bfly4_nw(float2& a, float2& b, float2& c, float2& d) {
    float2 apc = make_float2(a.x + c.x, a.y + c.y);
    float2 amc = make_float2(a.x - c.x, a.y - c.y);
    float2 bpd = make_float2(b.x + d.x, b.y + d.y);
    float2 bmd = make_float2(b.x - d.x, b.y - d.y);
    a = make_float2(apc.x + bpd.x, apc.y + bpd.y);
    b = make_float2(amc.x + bmd.y, amc.y - bmd.x);
    c = make_float2(apc.x - bpd.x, apc.y - bpd.y);
    d = make_float2(amc.x - bmd.y, amc.y + bmd.x);
}

// wave-internal LDS ordering fence (HW keeps a wave's DS ops in order;
// this pins the compiler; rule #18: sched_barrier after the waitcnt).
__device__ __forceinline__ void fence() {
    asm volatile("s_waitcnt lgkmcnt(0)" ::: "memory");
    __builtin_amdgcn_sched_barrier(0);
}

// spin until *p >= tgt (LDS counter). All lanes issue the same uniform read
// every ~128 cycles -> negligible LDS-pipe pressure.
__device__ __forceinline__ void spin_ge(const unsigned* p, unsigned tgt) {
    while (__hip_atomic_load(p, __ATOMIC_RELAXED, __HIP_MEMORY_SCOPE_WORKGROUP) < tgt)
        __builtin_amdgcn_s_sleep(2);
    __builtin_amdgcn_sched_barrier(0);
    asm volatile("" ::: "memory");
}

// ~17-instr atan2: v_rcp (1 ulp) + deg-11 minimax odd poly, err ~5e-6 rad.
__device__ __forceinline__ float fast_atan2f(float y, float x) {
    const float ax = fabsf(x), ay = fabsf(y);
    const float mx = fmaxf(ax, ay), mn = fminf(ax, ay);
    float r = mn * __builtin_amdgcn_rcpf(mx);
    if (mx == 0.0f) r = 0.0f;
    const float t = r * r;
    float p = fmaf(t, -0.01172120f, 0.05265332f);
    p = fmaf(t, p, -0.11643287f);
    p = fmaf(t, p, 0.19354346f);
    p = fmaf(t, p, -0.33262347f);
    p = fmaf(t, p, 0.99997726f);
    float a = r * p;
    a = (ay > ax) ? (1.5707963267948966f - a) : a;
    a = (x < 0.0f) ? (3.14159265358979323f - a) : a;
    return copysignf(a, y);
}

// exact /39 for 0 <= v < 2496 (verified at 38/39/78/1208/1209/1247)
__device__ __forceinline__ int div39(int v) { return (v * 26887) >> 20; }

__global__ __launch_bounds__(NT, 4)
void spec_kernel(const float* __restrict__ x, const float* __restrict__ win,
                 float* __restrict__ out)
{
    __shared__ __align__(16) float2 zb[2 * ABUF];   // 157,952 B (double buffer)
    __shared__ unsigned pc[2], cc[2];               // fill / consume counters

    const int tid  = threadIdx.x;
    const int wave = tid >> 6;
    const int ln   = tid & 63;

    // static XCD-chunked tile assignment: XCD c owns tiles [156c, 156c+156);
    // 32 blocks per XCD: 28 take 5 consecutive tiles, 4 take 4.
    const int xcd = blockIdx.x & 7;
    const int l   = blockIdx.x >> 3;
    int start, cnt;
    if (l < 28) { start = 156*xcd + 5*l;            cnt = 5; }
    else        { start = 156*xcd + 140 + 4*(l-28); cnt = 4; }

    if (tid < 2) { pc[tid] = 0; cc[tid] = 0; }
    __syncthreads();   // the only block-wide barrier

    if (wave < 8) {
        // ================= PRODUCER: wave wv owns packed array wv ==========
        const int wv = wave;
        float4 pa[4], pb[4];
        // initial prefetch (tile = start)
        {
            const int bb = div39(start);
            const int t0 = (start - 39*bb) * TILE_T;
            const float* xb = x + (size_t)bb * XLEN;
            const int f0 = t0 + 2*wv, f1 = f0 + 1;
            const bool v0 = (f0 < NFRAMES), v1 = (f1 < NFRAMES);
            #pragma unroll
            for (int q = 0; q < 4; ++q) {
                const int n0 = (q << 8) + (ln << 2);
                pa[q] = v0 ? *reinterpret_cast<const float4*>(&xb[f0*HOP + n0])
                           : make_float4(0.f,0.f,0.f,0.f);
                pb[q] = v1 ? *reinterpret_cast<const float4*>(&xb[f1*HOP + n0])
                           : make_float4(0.f,0.f,0.f,0.f);
            }
        }
        for (int e = 0; e < cnt; ++e) {
            const unsigned bsel = (unsigned)(e & 1);
            if (e >= 2) spin_ge(&cc[bsel], 8u * (unsigned)(e >> 1));
            float2* Z = zb + bsel * ABUF;

            // ---- stage: window + write own array ----
            {
                float4* D4 = reinterpret_cast<float4*>(
                    &Z[wv*ROW + 4*ln + 2*(ln>>2) + 4*(ln>>4)]);
                #pragma unroll
                for (int q = 0; q < 4; ++q) {
                    const int n0 = (q << 8) + (ln << 2);
                    const float4 w4 = *reinterpret_cast<const float4*>(&win[n0]);
                    D4[156*q]     = make_float4(w4.x*pa[q].x, w4.x*pb[q].x,
                                                w4.y*pa[q].y, w4.y*pb[q].y);
                    D4[156*q + 1] = make_float4(w4.z*pa[q].z, w4.z*pb[q].z,
                                                w4.w*pa[q].w, w4.w*pb[q].w);
                }
            }
            // ---- prefetch next tile's x (retires under the FFT below) ----
            if (e + 1 < cnt) {
                const int tile = start + e + 1;
                const int bb = div39(tile);
                const int t0 = (tile - 39*bb) * TILE_T;
                const float* xb = x + (size_t)bb * XLEN;
                const int f0 = t0 + 2*wv, f1 = f0 + 1;
                const bool v0 = (f0 < NFRAMES), v1 = (f1 < NFRAMES);
                #pragma unroll
                for (int q = 0; q < 4; ++q) {
                    const int n0 = (q << 8) + (ln << 2);
                    pa[q] = v0 ? *reinterpret_cast<const float4*>(&xb[f0*HOP + n0])
                               : make_float4(0.f,0.f,0.f,0.f);
                    pb[q] = v1 ? *reinterpret_cast<const float4*>(&xb[f1*HOP + n0])
                               : make_float4(0.f,0.f,0.f,0.f);
                }
            }
            fence();

            // ---- fused stages 0+1 (radix-16 in registers) ----
            {
                float2* p = &Z[wv*ROW + ln + 2*(ln>>4)];
                float2 E[16];
                #pragma unroll
                for (int j = 0; j < 16; ++j) E[j] = p[76*j + 8*(j>>2)];
                const float2 wc = w_of_rev((float)ln * (-1.0f/1024.0f));
                #pragma unroll
                for (int q = 0; q < 4; ++q) {
                    float2 w1;
                    if      (q == 0) w1 = wc;
                    else if (q == 1) w1 = cmul(wc, make_float2(C1, -S1));
                    else if (q == 2) w1 = cmul(wc, make_float2(C2, -C2));
                    else             w1 = cmul(wc, make_float2(S1, -C1));
                    float2 w2 = csqr(w1), w3 = cmul(w1, w2);
                    bfly4(E[q], E[q+4], E[q+8], E[q+12], w1, w2, w3);
                }
                const float2 wb  = csqr(csqr(wc));          // W_1024^{4ln}
                const float2 wb2 = csqr(wb), wb3 = cmul(wb, wb2);
                #pragma unroll
                for (int u = 0; u < 4; ++u)
                    bfly4(E[4*u], E[4*u+1], E[4*u+2], E[4*u+3], wb, wb2, wb3);
                #pragma unroll
                for (int j = 0; j < 16; ++j) p[76*j + 8*(j>>2)] = E[j];
            }
            fence();

            // ---- stage 2 (M=16) ----
            {
                const int m = ln & 15, h = ln >> 4;
                float2* p = &Z[wv*ROW + 76*h + m];
                const float2 w1 = w_of_rev((float)m * (-1.0f/64.0f));
                const float2 w2 = csqr(w1), w3 = cmul(w1, w2);
                #pragma unroll
                for (int u = 0; u < 4; ++u) {
                    float2 a  = p[312*u],      b2 = p[312*u + 18];
                    float2 c2 = p[312*u + 36], d2 = p[312*u + 54];
                    bfly4(a, b2, c2, d2, w1, w2, w3);
                    p[312*u]      = a;   p[312*u + 18] = b2;
                    p[312*u + 36] = c2;  p[312*u + 54] = d2;
                }
            }
            fence();

            // ---- fused stages 3+4 (registers, constant twiddles) ----
            {
                float4* p = reinterpret_cast<float4*>(
                    &Z[wv*ROW + 18*ln + 4*(ln>>2) + 8*(ln>>4)]);
                float2 F[16];
                #pragma unroll
                for (int r = 0; r < 8; ++r) {
                    const float4 v = p[r];
                    F[2*r]   = make_float2(v.x, v.y);
                    F[2*r+1] = make_float2(v.z, v.w);
                }
                bfly4_nw(F[0], F[4], F[8],  F[12]);
                bfly4(F[1], F[5], F[9],  F[13], make_float2(C1,-S1), make_float2(C2,-C2), make_float2(S1,-C1));
                bfly4(F[2], F[6], F[10], F[14], make_float2(C2,-C2), make_float2(0.f,-1.f), make_float2(-C2,-C2));
                bfly4(F[3], F[7], F[11], F[15], make_float2(S1,-C1), make_float2(-C2,-C2), make_float2(-C1, S1));
                bfly4_nw(F[0],  F[1],  F[2],  F[3]);
                bfly4_nw(F[4],  F[5],  F[6],  F[7]);
                bfly4_nw(F[8],  F[9],  F[10], F[11]);
                bfly4_nw(F[12], F[13], F[14], F[15]);
                #pragma unroll
                for (int r = 0; r < 8; ++r)
                    p[r] = make_float4(F[2*r].x, F[2*r].y, F[2*r+1].x, F[2*r+1].y);
            }
            fence();   // all writes in the wave's DS queue before the signal
            if (ln == 0)
                __hip_atomic_fetch_add(&pc[bsel], 1u, __ATOMIC_RELAXED,
                                       __HIP_MEMORY_SCOPE_WORKGROUP);
        }
    } else {
        // ================= CONSUMER: output phase of the previous fill =====
        const int ctid = tid - 512;
        const int kg   = ctid >> 3;        // 0..63
        const int jj   = ctid & 7;         // array == frame pair
        const int R1 = ((kg & 3) << 8) | ((kg & 12) << 4) | (kg & 48);
        const int km = 64 - kg;
        const int R2 = ((km & 3) << 8) | ((km & 12) << 4) | (km & 48);
        const int J0 = (kg == 0) ? 16 : 15;
        float* magp = out;                                       // [32][513][622]
        float* php  = out + (size_t)NBATCH * KBINS * NFRAMES;    // [32][1024][622]

        for (int e = 0; e < cnt; ++e) {
            const unsigned bsel = (unsigned)(e & 1);
            spin_ge(&pc[bsel], 8u * (unsigned)((e >> 1) + 1));
            const float2* Z = zb + bsel * ABUF;

            const int tile = start + e;
            const int bb = div39(tile);
            const int t0 = (tile - 39*bb) * TILE_T;
            const int t_e = t0 + 2*jj;
            const bool tval = (t_e < NFRAMES);

            const float2* zp1 = &Z[jj*ROW + PAD(R1)];
            const float2* zp2 = &Z[jj*ROW + PAD(R2)];
            const size_t magbase = (size_t)bb * KBINS * NFRAMES + t_e;
            const size_t phbase  = (size_t)bb * NFFT  * NFRAMES + t_e;

            if (tval) {
                #pragma unroll
                for (int it = 0; it < 9; ++it) {
                    if (it == 8 && kg != 0) break;          // only k=512 remains
                    const int k  = kg + (it << 6);
                    const int c1 = ((it & 3) << 2) | (it >> 2);   // rev4(64it)
                    const int j2 = (J0 - it) & 15;
                    const int c2 = ((j2 & 3) << 2) | (j2 >> 2);
                    const float2 z1 = zp1[c1];
                    const float2 z2 = zp2[c2];
                    const float re_e = 0.5f*(z1.x + z2.x);
                    const float im_e = 0.5f*(z1.y - z2.y);  // exact +0.0 at k=0,512
                    const float re_o = 0.5f*(z1.y + z2.y);
                    const float im_o = 0.5f*(z2.x - z1.x);
                    *reinterpret_cast<float2*>(&magp[magbase + (size_t)k * NFRAMES]) =
                        make_float2(fmaf(re_e, re_e, im_e*im_e),
                                    fmaf(re_o, re_o, im_o*im_o));
                    const float ph_e = fast_atan2f(im_e, re_e);
                    const float ph_o = fast_atan2f(im_o, re_o);
                    *reinterpret_cast<float2*>(&php[phbase + (size_t)k * NFRAMES]) =
                        make_float2(ph_e, ph_o);
                    if (k != 0 && k != 512) {
                        // atan2 odd in y INCLUDING signed zeros -> sign flip
                        *reinterpret_cast<float2*>(&php[phbase + (size_t)(NFFT - k) * NFRAMES]) =
                            make_float2(-ph_e, -ph_o);
                    }
                }
            }
            fence();   // LDS reads retired before the release signal
            if (ln == 0)
                __hip_atomic_fetch_add(&cc[bsel], 1u, __ATOMIC_RELAXED,
                                       __HIP_MEMORY_SCOPE_WORKGROUP);
        }
    }
}

extern "C" void kernel_launch(void* const* d_in, const int* in_sizes, int n_in,
                              void* d_out, int out_size, void* d_ws, size_t ws_size,
                              hipStream_t stream) {
    const float* x  = (const float*)d_in[0];
    const float* rw = (const float*)d_in[1];   // row 0 = fp32 hanning window
    float* out = (float*)d_out;
    spec_kernel<<<dim3(NBLK, 1, 1), dim3(NT, 1, 1), 0, stream>>>(x, rw, out);
}